// Round 10
// baseline (349.027 us; speedup 1.0000x reference)
//
#include <hip/hip_runtime.h>
#include <hip/hip_bf16.h>
#include <math.h>

#define N_ROI 8192
#define C_IN  1024
#define HIDD  256
#define FGD   64
#define CLSD  128
#define INV_TAU 5.0f
#define SCALE_LOG2E 7.2134752f   // 5 * log2(e)
#define LN2F 0.69314718f

using frag_ab = __attribute__((ext_vector_type(8))) short;   // 8 bf16 = 4 VGPRs
using f32x16  = __attribute__((ext_vector_type(16))) float;

static __device__ __forceinline__ short f32_to_bf16_bits(float f) {
  unsigned u = __builtin_bit_cast(unsigned, f);
  u = (u + 0x7FFFu + ((u >> 16) & 1u)) >> 16;   // RNE (inputs finite)
  return (short)u;
}
static __device__ __forceinline__ float bf16_bits_to_f32(short b) {
  unsigned u = ((unsigned)(unsigned short)b) << 16;
  return __builtin_bit_cast(float, u);
}
static __device__ __forceinline__ float fast_exp2(float x) {
#if __has_builtin(__builtin_amdgcn_exp2f)
  return __builtin_amdgcn_exp2f(x);
#else
  return exp2f(x);
#endif
}

// ---------------- L1: pack weights (fp32 -> bf16 frag order) + zero cnt ------
__global__ __launch_bounds__(256) void pack_zero_kernel(
    const float* __restrict__ w1f, const float* __restrict__ w1c,
    const float* __restrict__ w2f, const float* __restrict__ w2c,
    short* __restrict__ W1pf, short* __restrict__ W1pc,
    short* __restrict__ W2pf, short* __restrict__ W2pc,
    int* __restrict__ cnt) {
  int b = blockIdx.x;
  if (b == 280) {
    int t = threadIdx.x;
    if (t < 24) cnt[t] = 0;
    return;
  }
  const float* src; short* dst; int Ksh; int b0;
  if (b < 128)      { src = w1f; dst = W1pf; Ksh = 10; b0 = 0; }
  else if (b < 256) { src = w1c; dst = W1pc; Ksh = 10; b0 = 128; }
  else if (b < 264) { src = w2f; dst = W2pf; Ksh = 8;  b0 = 256; }
  else              { src = w2c; dst = W2pc; Ksh = 8;  b0 = 264; }
  int K = 1 << Ksh;
  int f = (b - b0) * 256 + threadIdx.x;
  int r = f >> (Ksh - 3);
  int c0 = (f & ((K >> 3) - 1)) << 3;
  float4 v0 = *(const float4*)(src + (size_t)r * K + c0);
  float4 v1 = *(const float4*)(src + (size_t)r * K + c0 + 4);
  union { short s[8]; uint4 v; } o;
  o.s[0] = f32_to_bf16_bits(v0.x); o.s[1] = f32_to_bf16_bits(v0.y);
  o.s[2] = f32_to_bf16_bits(v0.z); o.s[3] = f32_to_bf16_bits(v0.w);
  o.s[4] = f32_to_bf16_bits(v1.x); o.s[5] = f32_to_bf16_bits(v1.y);
  o.s[6] = f32_to_bf16_bits(v1.z); o.s[7] = f32_to_bf16_bits(v1.w);
  ((uint4*)dst)[(size_t)((r >> 5) * (K >> 4) + (c0 >> 4)) * 64 +
                ((c0 >> 3) & 1) * 32 + (r & 31)] = o.v;
}

// ---------------- phase-2 helper: gemm2+normalize+pack from LDS H tile ----------
// Single wave, no barriers. T2 row-major H: T2[r*264 + c], c in [0,256).
template<int D>
__device__ __forceinline__ void gemm2_from_lds(
    const short* __restrict__ T2,
    const short* __restrict__ W2p, const float* __restrict__ b2,
    short* __restrict__ Zr, float* __restrict__ tii,
    short* __restrict__ T, int gt) {
  int lane = threadIdx.x & 63;
  const frag_ab* Wv = (const frag_ab*)W2p;
  constexpr int NT = D / 32;
  frag_ab a[16];
  #pragma unroll
  for (int kc = 0; kc < 16; ++kc)
    a[kc] = *(const frag_ab*)&T2[(lane & 31) * 264 + kc * 16 + (lane >> 5) * 8];
  f32x16 acc[NT];
  #pragma unroll
  for (int j = 0; j < NT; ++j)
    #pragma unroll
    for (int q = 0; q < 16; ++q) acc[j][q] = 0.f;
  #pragma unroll
  for (int kc = 0; kc < 16; ++kc)
    #pragma unroll
    for (int j = 0; j < NT; ++j)
      acc[j] = __builtin_amdgcn_mfma_f32_32x32x16_bf16(a[kc], Wv[(j * 16 + kc) * 64 + lane], acc[j], 0, 0, 0);
  int c = lane & 31, h = lane >> 5;
  float bb[NT];
  #pragma unroll
  for (int j = 0; j < NT; ++j) bb[j] = b2[j * 32 + c];
  float s1[16];
  #pragma unroll
  for (int r = 0; r < 16; ++r) {
    s1[r] = 0.f;
    #pragma unroll
    for (int j = 0; j < NT; ++j) {
      float v = acc[j][r] + bb[j];
      s1[r] += v * v;
    }
  }
  #pragma unroll
  for (int r = 0; r < 16; ++r)
    #pragma unroll
    for (int m = 1; m < 32; m <<= 1) s1[r] += __shfl_xor(s1[r], m);
  float s2[16];
  #pragma unroll
  for (int r = 0; r < 16; ++r) s2[r] = 0.f;
  #pragma unroll
  for (int j = 0; j < NT; ++j) {
    int cl = j * 32 + c;
    #pragma unroll
    for (int g = 0; g < 4; ++g) {
      short q0, q1, q2, q3;
      #pragma unroll
      for (int e = 0; e < 4; ++e) {
        int r = g * 4 + e;
        float sc = 1.f / fmaxf(sqrtf(s1[r]), 1e-8f);
        short qb = f32_to_bf16_bits((acc[j][r] + bb[j]) * sc);
        float zf = bf16_bits_to_f32(qb);
        s2[r] += zf * zf;
        if (e == 0) q0 = qb; else if (e == 1) q1 = qb; else if (e == 2) q2 = qb; else q3 = qb;
      }
      *(short4*)&T[cl * 36 + 4 * h + 8 * g] = make_short4(q0, q1, q2, q3);
    }
  }
  #pragma unroll
  for (int r = 0; r < 16; ++r)
    #pragma unroll
    for (int m = 1; m < 32; m <<= 1) s2[r] += __shfl_xor(s2[r], m);
  if (c == 0) {
    #pragma unroll
    for (int r = 0; r < 16; ++r)
      tii[gt * 32 + (r & 3) + 8 * (r >> 2) + 4 * h] = s2[r];
  }
  uint4* Zv = (uint4*)Zr;
  #pragma unroll
  for (int k = 0; k < D / 16; ++k) {
    int c0 = (2 * k + h) * 8;
    union { short s[8]; uint4 u; } o;
    #pragma unroll
    for (int e = 0; e < 8; ++e) o.s[e] = T[(c0 + e) * 36 + c];
    Zv[(size_t)(gt * (D / 16) + k) * 64 + h * 32 + c] = o.u;
  }
}

// ---------------- L2: fused MLP, head-split: grid (256 row-tiles x 2 heads) ------
// 32 rows x 256 cols per block; 4 waves x 64-col strips; 2 blocks/CU.
__global__ __launch_bounds__(256) void fused_mlp_kernel(
    const float* __restrict__ X,
    const short* __restrict__ W1pf, const short* __restrict__ W1pc,
    const float* __restrict__ b1f, const float* __restrict__ b1c,
    const short* __restrict__ W2pf, const short* __restrict__ W2pc,
    const float* __restrict__ b2f, const float* __restrict__ b2c,
    short* __restrict__ Zrf, short* __restrict__ Zrc,
    float* __restrict__ tiif, float* __restrict__ tiic,
    const int* __restrict__ labels,
    float* __restrict__ Sfg, float* __restrict__ Pfg,
    float* __restrict__ Scls, float* __restrict__ SPc,
    float* __restrict__ pfv, float* __restrict__ nimv,
    float* __restrict__ ljmv, int* __restrict__ cnt) {
  __shared__ short stageA[2][1024];     // 4 KB
  __shared__ short T2[32 * 264];        // 16.9 KB row-major H (this head)
  __shared__ short Tw[128 * 36];        // 9.2 KB phase-2 transpose
  int tid = threadIdx.x, lane = tid & 63, wv = tid >> 6;
  int Mb = blockIdx.x, head = blockIdx.y;

  if (head == 0 && tid < 32) {
    int i = Mb * 32 + tid;
    Sfg[i] = 0.f; Pfg[i] = 0.f; Scls[i] = 0.f; SPc[i] = 0.f;
    int l = labels[i];
    pfv[i]  = (l > 0)  ? 1.f : 0.f;
    nimv[i] = (l != -1) ? 1.f : 0.f;
    ljmv[i] = (l > 0)  ? (float)l : -7.f;
    int b = l + 1; if (b < 0) b = 0; if (b > 21) b = 21;
    atomicAdd(&cnt[b], 1);
  }

  const short* Wp = head ? W1pc : W1pf;
  const float* b1 = head ? b1c  : b1f;
  const uint4* Wv4 = (const uint4*)Wp;
  int arow = tid >> 3;
  int ac4  = tid & 7;
  const float* Xp = X + (size_t)(Mb * 32 + arow) * C_IN + ac4 * 4;
  int aslot = ((ac4 >> 2) * 64 + ((ac4 >> 1) & 1) * 32 + arow) * 8 + (ac4 & 1) * 4;

  float4 av;
  frag_ab breg[2][4];                   // [bank][kci*2+nt], 64-col strip
  f32x16 acc[2];
  #pragma unroll
  for (int nt = 0; nt < 2; ++nt)
    #pragma unroll
    for (int q = 0; q < 16; ++q) acc[nt][q] = 0.f;

  auto loadA = [&](int c) { av = *(const float4*)(Xp + c * 32); };
  auto loadB = [&](int c, int s) {
    #pragma unroll
    for (int kci = 0; kci < 2; ++kci)
      #pragma unroll
      for (int nt = 0; nt < 2; ++nt)
        breg[s][kci * 2 + nt] =
            *(const frag_ab*)&Wv4[(size_t)((wv * 2 + nt) * 64 + c * 2 + kci) * 64 + lane];
  };
  auto storeA = [&](int buf) {
    *(short4*)&stageA[buf][aslot] =
        make_short4(f32_to_bf16_bits(av.x), f32_to_bf16_bits(av.y),
                    f32_to_bf16_bits(av.z), f32_to_bf16_bits(av.w));
  };
  auto domfma = [&](int buf, int bank) {
    frag_ab a0 = *(const frag_ab*)&stageA[buf][(0 * 64 + lane) * 8];
    frag_ab a1 = *(const frag_ab*)&stageA[buf][(1 * 64 + lane) * 8];
    #pragma unroll
    for (int nt = 0; nt < 2; ++nt)
      acc[nt] = __builtin_amdgcn_mfma_f32_32x32x16_bf16(a0, breg[bank][nt], acc[nt], 0, 0, 0);
    #pragma unroll
    for (int nt = 0; nt < 2; ++nt)
      acc[nt] = __builtin_amdgcn_mfma_f32_32x32x16_bf16(a1, breg[bank][2 + nt], acc[nt], 0, 0, 0);
  };

  loadA(0); loadB(0, 0); storeA(0);
  __syncthreads();
  for (int c = 0; c < 32; c += 2) {
    if (c + 1 < 32) { loadA(c + 1); loadB(c + 1, 1); }
    domfma(0, 0);
    if (c + 1 < 32) storeA(1);
    __syncthreads();
    if (c + 2 < 32) { loadA(c + 2); loadB(c + 2, 0); }
    domfma(1, 1);
    if (c + 2 < 32) storeA(0);
    __syncthreads();
  }
  {
    int cl31 = lane & 31, h = lane >> 5;
    #pragma unroll
    for (int nt = 0; nt < 2; ++nt) {
      int gc = wv * 64 + nt * 32 + cl31;
      float bb = b1[gc];
      #pragma unroll
      for (int q = 0; q < 16; ++q) {
        int row = (q & 3) + 8 * (q >> 2) + 4 * h;
        float x = fmaxf(acc[nt][q] + bb, 0.f);
        T2[row * 264 + gc] = f32_to_bf16_bits(x);
      }
    }
  }
  __syncthreads();

  if (wv == 0) {
    if (head == 0)
      gemm2_from_lds<FGD>(T2, W2pf, b2f, Zrf, tiif, Tw, Mb);
    else
      gemm2_from_lds<CLSD>(T2, W2pc, b2c, Zrc, tiic, Tw, Mb);
  }
}

// ---------------- L3: MFMA Gram loss (R8 direct-L2 version) + ticket finalize ----
template<int D, int MODE, int NJT>
__device__ __forceinline__ void loss_body(
    const short* __restrict__ Zr, const int* __restrict__ labels,
    const float* __restrict__ pfv, const float* __restrict__ nimv,
    const float* __restrict__ ljmv,
    float* __restrict__ Sg, float* __restrict__ Pg) {
  constexpr int KC = D / 16;
  int tid = threadIdx.x, lane = tid & 63, wv = tid >> 6;
  int itile = blockIdx.x * 4 + wv;
  const frag_ab* Zrv = (const frag_ab*)Zr;
  frag_ab a[KC];
  #pragma unroll
  for (int kc = 0; kc < KC; ++kc) {
    frag_ab t = Zrv[(itile * KC + kc) * 64 + lane];
    #pragma unroll
    for (int e = 0; e < 8; ++e)
      t[e] = f32_to_bf16_bits(bf16_bits_to_f32(t[e]) * SCALE_LOG2E);
    a[kc] = t;
  }
  float limf[16];
  if (MODE == 1) {
    #pragma unroll
    for (int r = 0; r < 16; ++r) {
      int row = (r & 3) + 8 * (r >> 2) + 4 * (lane >> 5);
      limf[r] = (float)labels[itile * 32 + row];
    }
  }
  float Ssum[16] = {}, Psum[16] = {};
  int jt0 = blockIdx.y * NJT;
  int jlane = lane & 31;

  #pragma unroll 2
  for (int kk = 0; kk < NJT; ++kk) {
    int jt = jt0 + kk;
    int j = jt * 32 + jlane;
    float pf = 0.f, nim = 0.f, ljm = 0.f;
    if (MODE == 0) pf = pfv[j];
    else { nim = nimv[j]; ljm = ljmv[j]; }
    f32x16 acc;
    #pragma unroll
    for (int q = 0; q < 16; ++q) acc[q] = 0.f;
    #pragma unroll
    for (int kc = 0; kc < KC; ++kc) {
      frag_ab b = Zrv[((size_t)jt * KC + kc) * 64 + lane];
      acc = __builtin_amdgcn_mfma_f32_32x32x16_bf16(a[kc], b, acc, 0, 0, 0);
    }
    #pragma unroll
    for (int rr = 0; rr < 16; ++rr) {
      float e = fast_exp2(acc[rr]);
      if (MODE == 0) {
        Ssum[rr] += e;
        Psum[rr] = fmaf(pf, e, Psum[rr]);
      } else {
        Ssum[rr] = fmaf(nim, e, Ssum[rr]);
        Psum[rr] += (limf[rr] == ljm) ? acc[rr] : 0.f;
      }
    }
  }
  #pragma unroll
  for (int r = 0; r < 16; ++r) {
    float s = Ssum[r], p = Psum[r];
    #pragma unroll
    for (int m = 1; m < 32; m <<= 1) { s += __shfl_xor(s, m); p += __shfl_xor(p, m); }
    if ((lane & 31) == 0) {
      if (MODE == 1) p *= LN2F;
      int row = (r & 3) + 8 * (r >> 2) + 4 * (lane >> 5);
      atomicAdd(&Sg[itile * 32 + row], s);
      atomicAdd(&Pg[itile * 32 + row], p);
    }
  }
}

static __device__ __forceinline__ float agent_load(const float* p) {
  return __hip_atomic_load(p, __ATOMIC_RELAXED, __HIP_MEMORY_SCOPE_AGENT);
}

__global__ __launch_bounds__(256, 4) void loss_kernel(
    const short* __restrict__ Zrf, const short* __restrict__ Zrc,
    const int* __restrict__ labels, const float* __restrict__ ious,
    const float* __restrict__ pfv, const float* __restrict__ nimv,
    const float* __restrict__ ljmv,
    float* __restrict__ Sfg, float* __restrict__ Pfg,
    float* __restrict__ Scls, float* __restrict__ SPc,
    const float* __restrict__ tiif, const float* __restrict__ tiic,
    int* __restrict__ cnt, float* __restrict__ out) {
  if (blockIdx.z == 0)
    loss_body<FGD, 0, 16>(Zrf, labels, pfv, nimv, ljmv, Sfg, Pfg);
  else
    loss_body<CLSD, 1, 16>(Zrc, labels, pfv, nimv, ljmv, Scls, SPc);

  // ---- ticket: last of 2048 blocks runs the finalize reduction ----
  __threadfence();
  __syncthreads();
  __shared__ int isLast;
  if (threadIdx.x == 0)
    isLast = (atomicAdd(&cnt[22], 1) == 2047);
  __syncthreads();
  if (!isLast) return;
  __threadfence();

  int cntP = 0;
  #pragma unroll
  for (int b = 2; b <= 21; ++b) cntP += cnt[b];
  int cntNI = N_ROI - cnt[0];
  float v0 = 0.f, v1 = 0.f, v2 = 0.f, v3 = 0.f;
  for (int i = threadIdx.x; i < N_ROI; i += 256) {
    int l = labels[i];
    float iv = ious[i];
    float w = (iv > 0.5f) ? iv : 0.f;
    bool Pi = (l > 0);
    float eF = __expf(INV_TAU * tiif[i]);
    float Sf = agent_load(&Sfg[i]) - eF;
    float Pf = agent_load(&Pfg[i]) - (Pi ? eF : 0.f);
    int nposF = cntP - (Pi ? 1 : 0);
    if (Pi && nposF > 0) {
      float lossF = logf((Sf + 1e-8f) / (Pf + 1e-8f));
      v0 += lossF * w; v1 += w;
    }
    float tC = INV_TAU * tiic[i];
    float eC = __expf(tC);
    float Sc = agent_load(&Scls[i]) - ((l != -1) ? eC : 0.f);
    float SP = agent_load(&SPc[i]) - (Pi ? tC : 0.f);
    int nposC = Pi ? (cnt[l + 1] - 1) : 0;
    bool anyv = (cntNI - ((l != -1) ? 1 : 0)) > 0;
    if (Pi && nposC > 0 && anyv) {
      float lse = logf(Sc);
      float lossC = -(SP - (float)nposC * lse) / fmaxf((float)nposC, 1.f);
      v2 += lossC * w; v3 += w;
    }
  }
  #pragma unroll
  for (int m = 1; m < 64; m <<= 1) {
    v0 += __shfl_xor(v0, m); v1 += __shfl_xor(v1, m);
    v2 += __shfl_xor(v2, m); v3 += __shfl_xor(v3, m);
  }
  __shared__ float red[4][4];
  int lane = threadIdx.x & 63, wid = threadIdx.x >> 6;
  if (lane == 0) { red[wid][0]=v0; red[wid][1]=v1; red[wid][2]=v2; red[wid][3]=v3; }
  __syncthreads();
  if (threadIdx.x == 0) {
    float s0=0,s1=0,s2=0,s3=0;
    for (int q = 0; q < 4; ++q) { s0+=red[q][0]; s1+=red[q][1]; s2+=red[q][2]; s3+=red[q][3]; }
    out[0] = s0 / (s1 + 1e-8f);
    out[1] = s2 / (s3 + 1e-12f);
  }
}

extern "C" void kernel_launch(void* const* d_in, const int* in_sizes, int n_in,
                              void* d_out, int out_size, void* d_ws, size_t ws_size,
                              hipStream_t stream) {
  const float* X    = (const float*)d_in[0];
  const int*  labels= (const int*)d_in[1];
  const float* ious = (const float*)d_in[2];
  const float* w1f  = (const float*)d_in[3];
  const float* b1f  = (const float*)d_in[4];
  const float* w2f  = (const float*)d_in[5];
  const float* b2f  = (const float*)d_in[6];
  const float* w1c  = (const float*)d_in[7];
  const float* b1c  = (const float*)d_in[8];
  const float* w2c  = (const float*)d_in[9];
  const float* b2c  = (const float*)d_in[10];
  float* out = (float*)d_out;

  char* w = (char*)d_ws;
  short* W1pf = (short*)w;            w += 524288;
  short* W1pc = (short*)w;            w += 524288;
  short* W2pf = (short*)w;            w += 32768;
  short* W2pc = (short*)w;            w += 65536;
  short* Zrf  = (short*)w;            w += 1048576;
  short* Zrc  = (short*)w;            w += 2097152;
  float* Sfg  = (float*)w;            w += 32768;
  float* Pfg  = (float*)w;            w += 32768;
  float* Scls = (float*)w;            w += 32768;
  float* SPc  = (float*)w;            w += 32768;
  float* tiif = (float*)w;            w += 32768;
  float* tiic = (float*)w;            w += 32768;
  float* pfv  = (float*)w;            w += 32768;
  float* nimv = (float*)w;            w += 32768;
  float* ljmv = (float*)w;            w += 32768;
  int*   cnt  = (int*)w;              w += 96;

  pack_zero_kernel<<<281, 256, 0, stream>>>(w1f, w1c, w2f, w2c,
                                            W1pf, W1pc, W2pf, W2pc, cnt);

  fused_mlp_kernel<<<dim3(256, 2), 256, 0, stream>>>(X, W1pf, W1pc, b1f, b1c,
                                            W2pf, W2pc, b2f, b2c,
                                            Zrf, Zrc, tiif, tiic,
                                            labels, Sfg, Pfg, Scls, SPc,
                                            pfv, nimv, ljmv, cnt);

  loss_kernel<<<dim3(64, 16, 2), 256, 0, stream>>>(Zrf, Zrc, labels, ious,
                                                   pfv, nimv, ljmv,
                                                   Sfg, Pfg, Scls, SPc,
                                                   tiif, tiic, cnt, out);
}

// Round 11
// 200.299 us; speedup vs baseline: 1.7425x; 1.7425x over previous
//
#include <hip/hip_runtime.h>
#include <hip/hip_bf16.h>
#include <math.h>

#define N_ROI 8192
#define C_IN  1024
#define HIDD  256
#define FGD   64
#define CLSD  128
#define INV_TAU 5.0f
#define SCALE_LOG2E 7.2134752f   // 5 * log2(e)
#define LN2F 0.69314718f

using frag_ab = __attribute__((ext_vector_type(8))) short;   // 8 bf16 = 4 VGPRs
using f32x16  = __attribute__((ext_vector_type(16))) float;

static __device__ __forceinline__ short f32_to_bf16_bits(float f) {
  unsigned u = __builtin_bit_cast(unsigned, f);
  u = (u + 0x7FFFu + ((u >> 16) & 1u)) >> 16;   // RNE (inputs finite)
  return (short)u;
}
static __device__ __forceinline__ float bf16_bits_to_f32(short b) {
  unsigned u = ((unsigned)(unsigned short)b) << 16;
  return __builtin_bit_cast(float, u);
}
static __device__ __forceinline__ float fast_exp2(float x) {
#if __has_builtin(__builtin_amdgcn_exp2f)
  return __builtin_amdgcn_exp2f(x);
#else
  return exp2f(x);
#endif
}

// ---------------- L1: pack weights (fp32 -> bf16 frag order) + zero accum/cnt ------
__global__ __launch_bounds__(256) void pack_zero_kernel(
    const float* __restrict__ w1f, const float* __restrict__ w1c,
    const float* __restrict__ w2f, const float* __restrict__ w2c,
    short* __restrict__ W1pf, short* __restrict__ W1pc,
    short* __restrict__ W2pf, short* __restrict__ W2pc,
    float* __restrict__ accum, int* __restrict__ cnt) {
  int b = blockIdx.x;
  if (b == 280) {
    int t = threadIdx.x;
    if (t < 8) accum[t] = 0.f;
    if (t < 24) cnt[t] = 0;
    return;
  }
  const float* src; short* dst; int Ksh; int b0;
  if (b < 128)      { src = w1f; dst = W1pf; Ksh = 10; b0 = 0; }
  else if (b < 256) { src = w1c; dst = W1pc; Ksh = 10; b0 = 128; }
  else if (b < 264) { src = w2f; dst = W2pf; Ksh = 8;  b0 = 256; }
  else              { src = w2c; dst = W2pc; Ksh = 8;  b0 = 264; }
  int K = 1 << Ksh;
  int f = (b - b0) * 256 + threadIdx.x;
  int r = f >> (Ksh - 3);
  int c0 = (f & ((K >> 3) - 1)) << 3;
  float4 v0 = *(const float4*)(src + (size_t)r * K + c0);
  float4 v1 = *(const float4*)(src + (size_t)r * K + c0 + 4);
  union { short s[8]; uint4 v; } o;
  o.s[0] = f32_to_bf16_bits(v0.x); o.s[1] = f32_to_bf16_bits(v0.y);
  o.s[2] = f32_to_bf16_bits(v0.z); o.s[3] = f32_to_bf16_bits(v0.w);
  o.s[4] = f32_to_bf16_bits(v1.x); o.s[5] = f32_to_bf16_bits(v1.y);
  o.s[6] = f32_to_bf16_bits(v1.z); o.s[7] = f32_to_bf16_bits(v1.w);
  ((uint4*)dst)[(size_t)((r >> 5) * (K >> 4) + (c0 >> 4)) * 64 +
                ((c0 >> 3) & 1) * 32 + (r & 31)] = o.v;
}

// ---------------- phase-2 helper: gemm2+normalize+pack from LDS H tile ----------
// Single wave, no barriers. T2 row-major H: T2[r*264 + c], c in [0,256).
template<int D>
__device__ __forceinline__ void gemm2_from_lds(
    const short* __restrict__ T2,
    const short* __restrict__ W2p, const float* __restrict__ b2,
    short* __restrict__ Zr, float* __restrict__ tii,
    short* __restrict__ T, int gt) {
  int lane = threadIdx.x & 63;
  const frag_ab* Wv = (const frag_ab*)W2p;
  constexpr int NT = D / 32;
  frag_ab a[16];
  #pragma unroll
  for (int kc = 0; kc < 16; ++kc)
    a[kc] = *(const frag_ab*)&T2[(lane & 31) * 264 + kc * 16 + (lane >> 5) * 8];
  f32x16 acc[NT];
  #pragma unroll
  for (int j = 0; j < NT; ++j)
    #pragma unroll
    for (int q = 0; q < 16; ++q) acc[j][q] = 0.f;
  #pragma unroll
  for (int kc = 0; kc < 16; ++kc)
    #pragma unroll
    for (int j = 0; j < NT; ++j)
      acc[j] = __builtin_amdgcn_mfma_f32_32x32x16_bf16(a[kc], Wv[(j * 16 + kc) * 64 + lane], acc[j], 0, 0, 0);
  int c = lane & 31, h = lane >> 5;
  float bb[NT];
  #pragma unroll
  for (int j = 0; j < NT; ++j) bb[j] = b2[j * 32 + c];
  float s1[16];
  #pragma unroll
  for (int r = 0; r < 16; ++r) {
    s1[r] = 0.f;
    #pragma unroll
    for (int j = 0; j < NT; ++j) {
      float v = acc[j][r] + bb[j];
      s1[r] += v * v;
    }
  }
  #pragma unroll
  for (int r = 0; r < 16; ++r)
    #pragma unroll
    for (int m = 1; m < 32; m <<= 1) s1[r] += __shfl_xor(s1[r], m);
  float s2[16];
  #pragma unroll
  for (int r = 0; r < 16; ++r) s2[r] = 0.f;
  #pragma unroll
  for (int j = 0; j < NT; ++j) {
    int cl = j * 32 + c;
    #pragma unroll
    for (int g = 0; g < 4; ++g) {
      short q0, q1, q2, q3;
      #pragma unroll
      for (int e = 0; e < 4; ++e) {
        int r = g * 4 + e;
        float sc = 1.f / fmaxf(sqrtf(s1[r]), 1e-8f);
        short qb = f32_to_bf16_bits((acc[j][r] + bb[j]) * sc);
        float zf = bf16_bits_to_f32(qb);
        s2[r] += zf * zf;
        if (e == 0) q0 = qb; else if (e == 1) q1 = qb; else if (e == 2) q2 = qb; else q3 = qb;
      }
      *(short4*)&T[cl * 36 + 4 * h + 8 * g] = make_short4(q0, q1, q2, q3);
    }
  }
  #pragma unroll
  for (int r = 0; r < 16; ++r)
    #pragma unroll
    for (int m = 1; m < 32; m <<= 1) s2[r] += __shfl_xor(s2[r], m);
  if (c == 0) {
    #pragma unroll
    for (int r = 0; r < 16; ++r)
      tii[gt * 32 + (r & 3) + 8 * (r >> 2) + 4 * h] = s2[r];
  }
  uint4* Zv = (uint4*)Zr;
  #pragma unroll
  for (int k = 0; k < D / 16; ++k) {
    int c0 = (2 * k + h) * 8;
    union { short s[8]; uint4 u; } o;
    #pragma unroll
    for (int e = 0; e < 8; ++e) o.s[e] = T[(c0 + e) * 36 + c];
    Zv[(size_t)(gt * (D / 16) + k) * 64 + h * 32 + c] = o.u;
  }
}

// ---------------- L2: fused MLP, head-split: grid (256 row-tiles x 2 heads) ------
__global__ __launch_bounds__(256) void fused_mlp_kernel(
    const float* __restrict__ X,
    const short* __restrict__ W1pf, const short* __restrict__ W1pc,
    const float* __restrict__ b1f, const float* __restrict__ b1c,
    const short* __restrict__ W2pf, const short* __restrict__ W2pc,
    const float* __restrict__ b2f, const float* __restrict__ b2c,
    short* __restrict__ Zrf, short* __restrict__ Zrc,
    float* __restrict__ tiif, float* __restrict__ tiic,
    const int* __restrict__ labels,
    float* __restrict__ Sfg, float* __restrict__ Pfg,
    float* __restrict__ Scls, float* __restrict__ SPc,
    float* __restrict__ pfv, float* __restrict__ nimv,
    float* __restrict__ ljmv, int* __restrict__ cnt) {
  __shared__ short stageA[2][1024];     // 4 KB
  __shared__ short T2[32 * 264];        // 16.9 KB row-major H (this head)
  __shared__ short Tw[128 * 36];        // 9.2 KB phase-2 transpose
  int tid = threadIdx.x, lane = tid & 63, wv = tid >> 6;
  int Mb = blockIdx.x, head = blockIdx.y;

  if (head == 0 && tid < 32) {
    int i = Mb * 32 + tid;
    Sfg[i] = 0.f; Pfg[i] = 0.f; Scls[i] = 0.f; SPc[i] = 0.f;
    int l = labels[i];
    pfv[i]  = (l > 0)  ? 1.f : 0.f;
    nimv[i] = (l != -1) ? 1.f : 0.f;
    ljmv[i] = (l > 0)  ? (float)l : -7.f;
    int b = l + 1; if (b < 0) b = 0; if (b > 21) b = 21;
    atomicAdd(&cnt[b], 1);
  }

  const short* Wp = head ? W1pc : W1pf;
  const float* b1 = head ? b1c  : b1f;
  const uint4* Wv4 = (const uint4*)Wp;
  int arow = tid >> 3;
  int ac4  = tid & 7;
  const float* Xp = X + (size_t)(Mb * 32 + arow) * C_IN + ac4 * 4;
  int aslot = ((ac4 >> 2) * 64 + ((ac4 >> 1) & 1) * 32 + arow) * 8 + (ac4 & 1) * 4;

  float4 av;
  frag_ab breg[2][4];                   // [bank][kci*2+nt], 64-col strip
  f32x16 acc[2];
  #pragma unroll
  for (int nt = 0; nt < 2; ++nt)
    #pragma unroll
    for (int q = 0; q < 16; ++q) acc[nt][q] = 0.f;

  auto loadA = [&](int c) { av = *(const float4*)(Xp + c * 32); };
  auto loadB = [&](int c, int s) {
    #pragma unroll
    for (int kci = 0; kci < 2; ++kci)
      #pragma unroll
      for (int nt = 0; nt < 2; ++nt)
        breg[s][kci * 2 + nt] =
            *(const frag_ab*)&Wv4[(size_t)((wv * 2 + nt) * 64 + c * 2 + kci) * 64 + lane];
  };
  auto storeA = [&](int buf) {
    *(short4*)&stageA[buf][aslot] =
        make_short4(f32_to_bf16_bits(av.x), f32_to_bf16_bits(av.y),
                    f32_to_bf16_bits(av.z), f32_to_bf16_bits(av.w));
  };
  auto domfma = [&](int buf, int bank) {
    frag_ab a0 = *(const frag_ab*)&stageA[buf][(0 * 64 + lane) * 8];
    frag_ab a1 = *(const frag_ab*)&stageA[buf][(1 * 64 + lane) * 8];
    #pragma unroll
    for (int nt = 0; nt < 2; ++nt)
      acc[nt] = __builtin_amdgcn_mfma_f32_32x32x16_bf16(a0, breg[bank][nt], acc[nt], 0, 0, 0);
    #pragma unroll
    for (int nt = 0; nt < 2; ++nt)
      acc[nt] = __builtin_amdgcn_mfma_f32_32x32x16_bf16(a1, breg[bank][2 + nt], acc[nt], 0, 0, 0);
  };

  loadA(0); loadB(0, 0); storeA(0);
  __syncthreads();
  for (int c = 0; c < 32; c += 2) {
    if (c + 1 < 32) { loadA(c + 1); loadB(c + 1, 1); }
    domfma(0, 0);
    if (c + 1 < 32) storeA(1);
    __syncthreads();
    if (c + 2 < 32) { loadA(c + 2); loadB(c + 2, 0); }
    domfma(1, 1);
    if (c + 2 < 32) storeA(0);
    __syncthreads();
  }
  {
    int cl31 = lane & 31, h = lane >> 5;
    #pragma unroll
    for (int nt = 0; nt < 2; ++nt) {
      int gc = wv * 64 + nt * 32 + cl31;
      float bb = b1[gc];
      #pragma unroll
      for (int q = 0; q < 16; ++q) {
        int row = (q & 3) + 8 * (q >> 2) + 4 * h;
        float x = fmaxf(acc[nt][q] + bb, 0.f);
        T2[row * 264 + gc] = f32_to_bf16_bits(x);
      }
    }
  }
  __syncthreads();

  if (wv == 0) {
    if (head == 0)
      gemm2_from_lds<FGD>(T2, W2pf, b2f, Zrf, tiif, Tw, Mb);
    else
      gemm2_from_lds<CLSD>(T2, W2pc, b2c, Zrc, tiic, Tw, Mb);
  }
}

// ---------------- L3: MFMA Gram loss (R8 direct-L2 version, NO fence/ticket) ------
template<int D, int MODE, int NJT>
__device__ __forceinline__ void loss_body(
    const short* __restrict__ Zr, const int* __restrict__ labels,
    const float* __restrict__ pfv, const float* __restrict__ nimv,
    const float* __restrict__ ljmv,
    float* __restrict__ Sg, float* __restrict__ Pg) {
  constexpr int KC = D / 16;
  int tid = threadIdx.x, lane = tid & 63, wv = tid >> 6;
  int itile = blockIdx.x * 4 + wv;
  const frag_ab* Zrv = (const frag_ab*)Zr;
  frag_ab a[KC];
  #pragma unroll
  for (int kc = 0; kc < KC; ++kc) {
    frag_ab t = Zrv[(itile * KC + kc) * 64 + lane];
    #pragma unroll
    for (int e = 0; e < 8; ++e)
      t[e] = f32_to_bf16_bits(bf16_bits_to_f32(t[e]) * SCALE_LOG2E);
    a[kc] = t;
  }
  float limf[16];
  if (MODE == 1) {
    #pragma unroll
    for (int r = 0; r < 16; ++r) {
      int row = (r & 3) + 8 * (r >> 2) + 4 * (lane >> 5);
      limf[r] = (float)labels[itile * 32 + row];
    }
  }
  float Ssum[16] = {}, Psum[16] = {};
  int jt0 = blockIdx.y * NJT;
  int jlane = lane & 31;

  #pragma unroll 2
  for (int kk = 0; kk < NJT; ++kk) {
    int jt = jt0 + kk;
    int j = jt * 32 + jlane;
    float pf = 0.f, nim = 0.f, ljm = 0.f;
    if (MODE == 0) pf = pfv[j];
    else { nim = nimv[j]; ljm = ljmv[j]; }
    f32x16 acc;
    #pragma unroll
    for (int q = 0; q < 16; ++q) acc[q] = 0.f;
    #pragma unroll
    for (int kc = 0; kc < KC; ++kc) {
      frag_ab b = Zrv[((size_t)jt * KC + kc) * 64 + lane];
      acc = __builtin_amdgcn_mfma_f32_32x32x16_bf16(a[kc], b, acc, 0, 0, 0);
    }
    #pragma unroll
    for (int rr = 0; rr < 16; ++rr) {
      float e = fast_exp2(acc[rr]);
      if (MODE == 0) {
        Ssum[rr] += e;
        Psum[rr] = fmaf(pf, e, Psum[rr]);
      } else {
        Ssum[rr] = fmaf(nim, e, Ssum[rr]);
        Psum[rr] += (limf[rr] == ljm) ? acc[rr] : 0.f;
      }
    }
  }
  #pragma unroll
  for (int r = 0; r < 16; ++r) {
    float s = Ssum[r], p = Psum[r];
    #pragma unroll
    for (int m = 1; m < 32; m <<= 1) { s += __shfl_xor(s, m); p += __shfl_xor(p, m); }
    if ((lane & 31) == 0) {
      if (MODE == 1) p *= LN2F;
      int row = (r & 3) + 8 * (r >> 2) + 4 * (lane >> 5);
      atomicAdd(&Sg[itile * 32 + row], s);
      atomicAdd(&Pg[itile * 32 + row], p);
    }
  }
}

__global__ __launch_bounds__(256, 4) void loss_kernel(
    const short* __restrict__ Zrf, const short* __restrict__ Zrc,
    const int* __restrict__ labels,
    const float* __restrict__ pfv, const float* __restrict__ nimv,
    const float* __restrict__ ljmv,
    float* __restrict__ Sfg, float* __restrict__ Pfg,
    float* __restrict__ Scls, float* __restrict__ SPc) {
  if (blockIdx.z == 0)
    loss_body<FGD, 0, 16>(Zrf, labels, pfv, nimv, ljmv, Sfg, Pfg);
  else
    loss_body<CLSD, 1, 16>(Zrc, labels, pfv, nimv, ljmv, Scls, SPc);
}

// ---------------- L4: per-row losses + weighted reduction + write-out ------------
__global__ __launch_bounds__(256) void finalize_kernel(
    const float* __restrict__ Sfg, const float* __restrict__ Pfg,
    const float* __restrict__ Scls, const float* __restrict__ SPc,
    const float* __restrict__ tiif, const float* __restrict__ tiic,
    const int* __restrict__ labels, const float* __restrict__ ious,
    int* __restrict__ cnt, float* __restrict__ accum, float* __restrict__ out) {
  int i = blockIdx.x * 256 + threadIdx.x;
  int l = labels[i];
  float iv = ious[i];
  float w = (iv > 0.5f) ? iv : 0.f;
  int cntP = 0;
  #pragma unroll
  for (int b = 2; b <= 21; ++b) cntP += cnt[b];
  int cntNI = N_ROI - cnt[0];
  bool Pi = (l > 0);
  float numF = 0.f, denF = 0.f, numC = 0.f, denC = 0.f;
  float eF = __expf(INV_TAU * tiif[i]);
  float Sf = Sfg[i] - eF;
  float Pf = Pfg[i] - (Pi ? eF : 0.f);
  int nposF = cntP - (Pi ? 1 : 0);
  if (Pi && nposF > 0) {
    float lossF = logf((Sf + 1e-8f) / (Pf + 1e-8f));
    numF = lossF * w; denF = w;
  }
  float tC = INV_TAU * tiic[i];
  float eC = __expf(tC);
  float Sc = Scls[i] - ((l != -1) ? eC : 0.f);
  float SP = SPc[i] - (Pi ? tC : 0.f);
  int nposC = Pi ? (cnt[l + 1] - 1) : 0;
  bool anyv = (cntNI - ((l != -1) ? 1 : 0)) > 0;
  if (Pi && nposC > 0 && anyv) {
    float lse = logf(Sc);
    float lossC = -(SP - (float)nposC * lse) / fmaxf((float)nposC, 1.f);
    numC = lossC * w; denC = w;
  }
  float v0 = numF, v1 = denF, v2 = numC, v3 = denC;
  #pragma unroll
  for (int m = 1; m < 64; m <<= 1) {
    v0 += __shfl_xor(v0, m); v1 += __shfl_xor(v1, m);
    v2 += __shfl_xor(v2, m); v3 += __shfl_xor(v3, m);
  }
  __shared__ float red[4][4];
  int lane = threadIdx.x & 63, wid = threadIdx.x >> 6;
  if (lane == 0) { red[wid][0]=v0; red[wid][1]=v1; red[wid][2]=v2; red[wid][3]=v3; }
  __syncthreads();
  if (threadIdx.x == 0) {
    float s0=0,s1=0,s2=0,s3=0;
    for (int q = 0; q < 4; ++q) { s0+=red[q][0]; s1+=red[q][1]; s2+=red[q][2]; s3+=red[q][3]; }
    atomicAdd(&accum[0], s0); atomicAdd(&accum[1], s1);
    atomicAdd(&accum[2], s2); atomicAdd(&accum[3], s3);
    __threadfence();
    int t = atomicAdd(&cnt[22], 1);
    if (t == 31) {
      __threadfence();
      out[0] = accum[0] / (accum[1] + 1e-8f);
      out[1] = accum[2] / (accum[3] + 1e-12f);
    }
  }
}

extern "C" void kernel_launch(void* const* d_in, const int* in_sizes, int n_in,
                              void* d_out, int out_size, void* d_ws, size_t ws_size,
                              hipStream_t stream) {
  const float* X    = (const float*)d_in[0];
  const int*  labels= (const int*)d_in[1];
  const float* ious = (const float*)d_in[2];
  const float* w1f  = (const float*)d_in[3];
  const float* b1f  = (const float*)d_in[4];
  const float* w2f  = (const float*)d_in[5];
  const float* b2f  = (const float*)d_in[6];
  const float* w1c  = (const float*)d_in[7];
  const float* b1c  = (const float*)d_in[8];
  const float* w2c  = (const float*)d_in[9];
  const float* b2c  = (const float*)d_in[10];
  float* out = (float*)d_out;

  char* w = (char*)d_ws;
  short* W1pf = (short*)w;            w += 524288;
  short* W1pc = (short*)w;            w += 524288;
  short* W2pf = (short*)w;            w += 32768;
  short* W2pc = (short*)w;            w += 65536;
  short* Zrf  = (short*)w;            w += 1048576;
  short* Zrc  = (short*)w;            w += 2097152;
  float* Sfg  = (float*)w;            w += 32768;
  float* Pfg  = (float*)w;            w += 32768;
  float* Scls = (float*)w;            w += 32768;
  float* SPc  = (float*)w;            w += 32768;
  float* tiif = (float*)w;            w += 32768;
  float* tiic = (float*)w;            w += 32768;
  float* pfv  = (float*)w;            w += 32768;
  float* nimv = (float*)w;            w += 32768;
  float* ljmv = (float*)w;            w += 32768;
  float* accum= (float*)w;            w += 32;
  int*   cnt  = (int*)w;              w += 96;

  pack_zero_kernel<<<281, 256, 0, stream>>>(w1f, w1c, w2f, w2c,
                                            W1pf, W1pc, W2pf, W2pc, accum, cnt);

  fused_mlp_kernel<<<dim3(256, 2), 256, 0, stream>>>(X, W1pf, W1pc, b1f, b1c,
                                            W2pf, W2pc, b2f, b2c,
                                            Zrf, Zrc, tiif, tiic,
                                            labels, Sfg, Pfg, Scls, SPc,
                                            pfv, nimv, ljmv, cnt);

  loss_kernel<<<dim3(64, 16, 2), 256, 0, stream>>>(Zrf, Zrc, labels, pfv, nimv, ljmv,
                                                   Sfg, Pfg, Scls, SPc);

  finalize_kernel<<<N_ROI/256, 256, 0, stream>>>(Sfg, Pfg, Scls, SPc, tiif, tiic,
                                                 labels, ious, cnt, accum, out);
}